// Round 20
// baseline (5342.207 us; speedup 1.0000x reference)
//
#include <hip/hip_runtime.h>
#include <math.h>

// DecoderTopDown beam-search decoder, round 20: R19 (5.26ms) with the GEMM LDS
// double-buffered: one barrier per chunk (was two); load latency hides under
// the MFMA block. LDS 70.7KB (2 blocks/CU - grid-limited anyway). MFMA order
// unchanged -> numerics identical to R19.
#define BB 32
#define KB 3
#define TT 20
#define VV 10000
#define RR 36
#define ED 512
#define VD 2048
#define HH 1024
#define PH_ 256
#define ROWS 96
#define EOS_TOK 2

typedef double f64x4 __attribute__((ext_vector_type(4)));

struct Seg { const double* X; const float* W; int ldx; int ldw; int woff; int kbeg; };
struct GemmA { Seg seg[3]; int nseg; int Mtot; int N; int Ktot; };

#define GBN 64
#define GKC 32
#define PX 34   // X row pad (doubles)
#define PW 36   // W row pad (floats)

// Probe the C/D fragment layout of v_mfma_f64_16x16x4 (proven R17).
__global__ void mfma_probe(int* __restrict__ rowmap, int* __restrict__ colmap) {
  int lane = threadIdx.x & 63;
  f64x4 z = {0.0, 0.0, 0.0, 0.0};
  double a1 = (double)(lane & 15), b1 = 1.0;
  f64x4 d1 = __builtin_amdgcn_mfma_f64_16x16x4f64(a1, b1, z, 0, 0, 0);
  double a2 = 1.0, b2 = (double)(lane & 15);
  f64x4 d2 = __builtin_amdgcn_mfma_f64_16x16x4f64(a2, b2, z, 0, 0, 0);
#pragma unroll
  for (int r = 0; r < 4; ++r) {
    rowmap[lane * 4 + r] = (int)(d1[r] * 0.25 + 0.5);
    colmap[lane * 4 + r] = (int)(d2[r] * 0.25 + 0.5);
  }
}

__global__ __launch_bounds__(256) void gemm_f64(GemmA a, double* __restrict__ part,
    const int* __restrict__ rowmap, const int* __restrict__ colmap) {
  __shared__ double Xs[2][96][PX];
  __shared__ float  Ws[2][GBN][PW];
  const int tid = threadIdx.x;
  const int n0 = blockIdx.x * GBN;
  const int s = blockIdx.y;
  const int m0 = blockIdx.z * 96;
  const int S = gridDim.y;
  const int ck = a.Ktot / S;        // host: divisible, multiple of GKC
  const int ks = s * ck;
  const int nch = ck / GKC;
  const int wave = tid >> 6, lane = tid & 63;
  const int lrow = lane & 15, lk = lane >> 4;
  const int xo = (lrow >> 3) & 1;          // X read swizzle offset
  const int wo = ((lrow >> 3) & 1) << 1;   // W read swizzle offset

  f64x4 acc[6];
#pragma unroll
  for (int r = 0; r < 6; ++r) acc[r] = (f64x4){0.0, 0.0, 0.0, 0.0};

  double2 xst[6];
  float4 wst[2];

  auto issue = [&](int k0) {
    int si = 0;
    for (int i = 1; i < a.nseg; ++i) if (k0 >= a.seg[i].kbeg) si = i;
    Seg sg = a.seg[si];
    int kl = k0 - sg.kbeg;
#pragma unroll
    for (int j = 0; j < 6; ++j) {      // X: 96 rows x 16 double2 cols
      int i = tid + 256 * j;
      int m = i >> 4, q = (i & 15) << 1;
      int mg = m0 + m;
      double2 v; v.x = 0.0; v.y = 0.0;
      if (mg < a.Mtot) v = *(const double2*)&sg.X[(size_t)mg * sg.ldx + kl + q];
      xst[j] = v;
    }
#pragma unroll
    for (int j = 0; j < 2; ++j) {      // W: 64 rows x 8 float4 cols
      int i = tid + 256 * j;
      int n = i >> 3, q = (i & 7) << 2;
      int ng = n0 + n;
      float4 v = {0.f, 0.f, 0.f, 0.f};
      if (ng < a.N) v = *(const float4*)&sg.W[(size_t)ng * sg.ldw + sg.woff + kl + q];
      wst[j] = v;
    }
  };

  auto stage = [&](int buf) {
#pragma unroll
    for (int j = 0; j < 6; ++j) {
      int i = tid + 256 * j;
      int m = i >> 4, q = (i & 15) << 1;
      int o = (m >> 3) & 1;
      Xs[buf][m][q + o] = xst[j].x;
      Xs[buf][m][q + 1 + o] = xst[j].y;
    }
#pragma unroll
    for (int j = 0; j < 2; ++j) {
      int i = tid + 256 * j;
      int n = i >> 3, q = (i & 7) << 2;
      int o = ((n >> 3) & 1) << 1;
      Ws[buf][n][q + o] = wst[j].x;
      Ws[buf][n][q + 1 + o] = wst[j].y;
      Ws[buf][n][q + 2 + o] = wst[j].z;
      Ws[buf][n][q + 3 + o] = wst[j].w;
    }
  };

  issue(ks);
  stage(0);
  for (int ch = 0; ch < nch; ++ch) {
    __syncthreads();                 // buf[ch&1] fully staged; prev reads done
    if (ch + 1 < nch) issue(ks + (ch + 1) * GKC);
    const int cur = ch & 1;
#pragma unroll
    for (int kq = 0; kq < GKC; kq += 4) {
      double b = (double)Ws[cur][16 * wave + lrow][kq + lk + wo];
#pragma unroll
      for (int r = 0; r < 6; ++r) {
        double av = Xs[cur][16 * r + lrow][kq + lk + xo];
        acc[r] = __builtin_amdgcn_mfma_f64_16x16x4f64(av, b, acc[r], 0, 0, 0);
      }
    }
    if (ch + 1 < nch) stage(cur ^ 1);
  }
  int rmap[4], cmap[4];
#pragma unroll
  for (int i = 0; i < 4; ++i) { rmap[i] = rowmap[lane * 4 + i]; cmap[i] = colmap[lane * 4 + i]; }
#pragma unroll
  for (int r = 0; r < 6; ++r) {
#pragma unroll
    for (int i = 0; i < 4; ++i) {
      int mg = m0 + 16 * r + rmap[i];
      int col = n0 + 16 * wave + cmap[i];
      if (mg < a.Mtot && col < a.N)
        part[((size_t)s * a.Mtot + mg) * a.N + col] = acc[r][i];
    }
  }
}

__global__ void convf_kernel(const float* __restrict__ s, double* __restrict__ d, int n) {
  int i = blockIdx.x * 256 + threadIdx.x;
  if (i < n) d[i] = (double)s[i];
}

__global__ void conv_kernel(const float* b1, const float* b2, const float* bva,
                            const float* bha, const float* wa, const float* bout,
                            double* b1d, double* b2d, double* bvad,
                            double* bhad, double* wad, double* boutd) {
  int i = blockIdx.x * 256 + threadIdx.x;
  if (i < 4 * HH) { b1d[i] = (double)b1[i]; b2d[i] = (double)b2[i]; }
  if (i < PH_) { bvad[i] = (double)bva[i]; bhad[i] = (double)bha[i]; wad[i] = (double)wa[i]; }
  if (i < VV) boutd[i] = (double)bout[i];
}

__global__ void init_kernel(double* h1s, double* c1s, double* h2s, double* c2s,
                            int* tok, double* lpt, int* fin, int* trj) {
  int idx = blockIdx.x * 256 + threadIdx.x;
  if (idx < ROWS * HH) { h1s[idx] = 0.0; c1s[idx] = 0.0; h2s[idx] = 0.0; c2s[idx] = 0.0; }
  if (idx < ROWS) { tok[idx] = 1; lpt[idx] = 0.0; fin[idx] = 0; }
  if (idx < ROWS * TT) trj[idx] = 0;
}

__global__ void vmean_kernel(const float* __restrict__ features, double* __restrict__ vme) {
  int idx = blockIdx.x * 256 + threadIdx.x;
  if (idx >= BB * VD) return;
  int b = idx / VD, d = idx - b * VD;
  double sum = 0.0;
  for (int r = 0; r < RR; ++r) sum += (double)features[((size_t)b * RR + r) * VD + d];
  vme[idx] = sum / (double)RR;
}

__global__ void reduce_bias_kernel(double* __restrict__ out, const double* __restrict__ parts,
                                   const double* __restrict__ bias, int rows, int cols, int S) {
  int idx = blockIdx.x * 256 + threadIdx.x;
  if (idx >= rows * cols) return;
  int c = idx % cols;
  double acc = bias[c];
  for (int s = 0; s < S; ++s) acc += parts[(size_t)s * rows * cols + idx];
  out[idx] = acc;
}

__global__ void embed_kernel(const int* __restrict__ tok, const float* __restrict__ E,
                             double* __restrict__ emb) {
  int idx = blockIdx.x * 256 + threadIdx.x;
  if (idx >= ROWS * ED) return;
  int row = idx >> 9, e2 = idx & (ED - 1);
  emb[idx] = (double)E[(size_t)tok[row] * ED + e2];
}

__global__ void lstm_kernel(const double* __restrict__ gP, int S,
                            const double* __restrict__ bias_col, const double* __restrict__ bias_row,
                            const double* __restrict__ c_in, double* __restrict__ h_out,
                            double* __restrict__ c_out) {
  int idx = blockIdx.x * 256 + threadIdx.x;
  if (idx >= ROWS * (HH / 2)) return;
  int row = idx >> 9, jj = (idx & 511) << 1;
  int b = row / KB;
  double2 g[4];
#pragma unroll
  for (int gi = 0; gi < 4; ++gi) {
    double2 acc;
    if (bias_col) acc = *(const double2*)&bias_col[gi * HH + jj];
    else          acc = *(const double2*)&bias_row[(size_t)b * 4 * HH + gi * HH + jj];
    for (int s = 0; s < S; ++s) {
      double2 p = *(const double2*)&gP[((size_t)s * ROWS + row) * (4 * HH) + gi * HH + jj];
      acc.x += p.x; acc.y += p.y;
    }
    g[gi] = acc;
  }
  double2 cp = *(const double2*)&c_in[((size_t)row << 10) + jj];
  double2 hv, cv;
  {
    double ig = 1.0 / (1.0 + exp(-g[0].x)), fg = 1.0 / (1.0 + exp(-g[1].x));
    double gg = tanh(g[2].x), og = 1.0 / (1.0 + exp(-g[3].x));
    cv.x = fg * cp.x + ig * gg; hv.x = og * tanh(cv.x);
  }
  {
    double ig = 1.0 / (1.0 + exp(-g[0].y)), fg = 1.0 / (1.0 + exp(-g[1].y));
    double gg = tanh(g[2].y), og = 1.0 / (1.0 + exp(-g[3].y));
    cv.y = fg * cp.y + ig * gg; hv.y = og * tanh(cv.y);
  }
  *(double2*)&h_out[((size_t)row << 10) + jj] = hv;
  *(double2*)&c_out[((size_t)row << 10) + jj] = cv;
}

__global__ __launch_bounds__(256) void attn_kernel(const double* __restrict__ hpP, int S,
    const double* __restrict__ bha, const double* __restrict__ featP,
    const float* __restrict__ features, const double* __restrict__ wa,
    double* __restrict__ vhat) {
  int row = blockIdx.x;
  int b = row / KB;
  int tid = threadIdx.x;
  __shared__ double hp[PH_];
  __shared__ double e[RR];
  {
    double v = bha[tid];
    for (int s = 0; s < S; ++s) v += hpP[((size_t)s * ROWS + row) * PH_ + tid];
    hp[tid] = v;
  }
  __syncthreads();
  int wv = tid >> 6, ln = tid & 63;
  for (int r = wv * 9; r < wv * 9 + 9; ++r) {
    double p = 0.0;
#pragma unroll
    for (int i = 0; i < 4; ++i) {
      int ph = ln * 4 + i;
      p += tanh(featP[((size_t)b * RR + r) * PH_ + ph] + hp[ph]) * wa[ph];
    }
#pragma unroll
    for (int o = 32; o; o >>= 1) p += __shfl_down(p, o);
    if (ln == 0) e[r] = p;
  }
  __syncthreads();
  if (tid == 0) {
    double m = e[0];
    for (int r = 1; r < RR; ++r) m = fmax(m, e[r]);
    double se = 0.0;
    for (int r = 0; r < RR; ++r) se += exp(e[r] - m);
    for (int r = 0; r < RR; ++r) e[r] = exp(e[r] - m) / se;
  }
  __syncthreads();
  for (int d = tid; d < VD; d += 256) {
    double acc2 = 0.0;
    for (int r = 0; r < RR; ++r) acc2 += e[r] * (double)features[((size_t)b * RR + r) * VD + d];
    vhat[(size_t)row * VD + d] = acc2;
  }
}

__device__ inline double wred_maxd(double v) {
#pragma unroll
  for (int o = 32; o; o >>= 1) v = fmax(v, __shfl_down(v, o));
  return v;
}
__device__ inline double wred_sumd(double v) {
#pragma unroll
  for (int o = 32; o; o >>= 1) v += __shfl_down(v, o);
  return v;
}

__device__ inline bool better(double va, int ia, double vb, int ib) {
  if (va != vb) return va > vb;
  return (unsigned)ia < (unsigned)ib;
}

__global__ __launch_bounds__(256) void lchunk_kernel(const double* __restrict__ lP, int S,
    const double* __restrict__ bout, const int* __restrict__ tok_old, int t,
    double* __restrict__ cm, double* __restrict__ cs,
    double* __restrict__ cv, int* __restrict__ ci) {
  const int CHV = VV / 8;   // 1250
  int row = blockIdx.x, chk = blockIdx.y, tid = threadIdx.x;
  int v0 = chk * CHV;
  int tokp = tok_old[row];
  double r[5];
  double lmax = -1.0e300;
#pragma unroll
  for (int j = 0; j < 5; ++j) {
    int vv = tid + (j << 8);
    double acc = -1.0e300;
    if (vv < CHV) {
      int v = v0 + vv;
      acc = bout[v];
      for (int s = 0; s < S; ++s) acc += lP[((size_t)s * ROWS + row) * VV + v];
      lmax = fmax(lmax, acc);
    }
    r[j] = acc;
  }
  __shared__ double red[4];
  double m = wred_maxd(lmax);
  if ((tid & 63) == 0) red[tid >> 6] = m;
  __syncthreads();
  m = fmax(fmax(red[0], red[1]), fmax(red[2], red[3]));
  double se = 0.0;
#pragma unroll
  for (int j = 0; j < 5; ++j) {
    int vv = tid + (j << 8);
    if (vv < CHV) se += exp(r[j] - m);
  }
  se = wred_sumd(se);
  __syncthreads();
  if ((tid & 63) == 0) red[tid >> 6] = se;
  __syncthreads();
  se = red[0] + red[1] + red[2] + red[3];
  double lv[3] = {-INFINITY, -INFINITY, -INFINITY};
  int li[3] = {-1, -1, -1};
#pragma unroll
  for (int j = 0; j < 5; ++j) {
    int vv = tid + (j << 8);
    if (vv >= CHV) continue;
    int v = v0 + vv;
    double sc = r[j];
    if (t > 0 && v == tokp) sc -= 1e4;
    if (better(sc, v, lv[2], li[2])) {
      if (better(sc, v, lv[1], li[1])) {
        lv[2] = lv[1]; li[2] = li[1];
        if (better(sc, v, lv[0], li[0])) { lv[1] = lv[0]; li[1] = li[0]; lv[0] = sc; li[0] = v; }
        else { lv[1] = sc; li[1] = v; }
      } else { lv[2] = sc; li[2] = v; }
    }
  }
  __shared__ double sv[256 * 3];
  __shared__ int si[256 * 3];
  sv[tid * 3 + 0] = lv[0]; sv[tid * 3 + 1] = lv[1]; sv[tid * 3 + 2] = lv[2];
  si[tid * 3 + 0] = li[0]; si[tid * 3 + 1] = li[1]; si[tid * 3 + 2] = li[2];
  for (int off2 = 128; off2 >= 1; off2 >>= 1) {
    __syncthreads();
    if (tid < off2) {
      double av[3], bv2[3]; int ai3[3], bi3[3];
#pragma unroll
      for (int j = 0; j < 3; ++j) {
        av[j] = sv[tid * 3 + j]; ai3[j] = si[tid * 3 + j];
        bv2[j] = sv[(tid + off2) * 3 + j]; bi3[j] = si[(tid + off2) * 3 + j];
      }
      double mv[3]; int mi[3];
      int ai = 0, bi = 0;
#pragma unroll
      for (int o = 0; o < 3; ++o) {
        if (better(av[ai], ai3[ai], bv2[bi], bi3[bi])) { mv[o] = av[ai]; mi[o] = ai3[ai]; ++ai; }
        else { mv[o] = bv2[bi]; mi[o] = bi3[bi]; ++bi; }
      }
#pragma unroll
      for (int j = 0; j < 3; ++j) { sv[tid * 3 + j] = mv[j]; si[tid * 3 + j] = mi[j]; }
    }
  }
  __syncthreads();
  if (tid == 0) {
    int o = row * 8 + chk;
    cm[o] = m; cs[o] = se;
    cv[o * 3 + 0] = sv[0]; cv[o * 3 + 1] = sv[1]; cv[o * 3 + 2] = sv[2];
    ci[o * 3 + 0] = si[0]; ci[o * 3 + 1] = si[1]; ci[o * 3 + 2] = si[2];
  }
}

__global__ __launch_bounds__(64) void topk2_kernel(
    const double* __restrict__ cm, const double* __restrict__ cs,
    const double* __restrict__ cv, const int* __restrict__ ci,
    const double* __restrict__ lpt_old, const int* __restrict__ fin_old,
    const int* __restrict__ trj_old, int t,
    int* __restrict__ tok_new, double* __restrict__ lpt_new, int* __restrict__ fin_new,
    int* __restrict__ trj_new, int* __restrict__ parent) {
  int b = blockIdx.x, tid = threadIdx.x;
  __shared__ double candv[72];
  __shared__ int candi[72];
  __shared__ int cnt[3];
  __shared__ int fink[3];
  __shared__ int sp[3], stk[3];
  if (tid < KB) {
    int row = b * KB + tid;
    double lpt = lpt_old[row];
    int fin = fin_old[row];
    fink[tid] = fin;
    int base = tid * 24;
    if (t == 0 && tid > 0) {
      cnt[tid] = 0;
    } else if (fin) {
      candv[base] = lpt;
      candi[base] = tid * VV + EOS_TOK;
      cnt[tid] = 1;
    } else {
      double M = -1.0e300;
      for (int c = 0; c < 8; ++c) M = fmax(M, cm[row * 8 + c]);
      double SE = 0.0;
      for (int c = 0; c < 8; ++c) SE += cs[row * 8 + c] * exp(cm[row * 8 + c] - M);
      double l = log(SE);
      int n = 0;
      for (int c = 0; c < 8; ++c) {
#pragma unroll
        for (int s3 = 0; s3 < 3; ++s3) {
          double val = cv[(row * 8 + c) * 3 + s3];
          int idx = ci[(row * 8 + c) * 3 + s3];
          candv[base + n] = lpt + ((val - M) - l);
          candi[base + n] = tid * VV + idx;
          ++n;
        }
      }
      cnt[tid] = n;
    }
  }
  __syncthreads();
  if (tid == 0) {
    double bv[3] = {-INFINITY, -INFINITY, -INFINITY};
    int bi2[3] = {-1, -1, -1};
    for (int k = 0; k < KB; ++k) {
      for (int j = 0; j < cnt[k]; ++j) {
        double sc = candv[k * 24 + j];
        int idx = candi[k * 24 + j];
        if (better(sc, idx, bv[2], bi2[2])) {
          if (better(sc, idx, bv[1], bi2[1])) {
            bv[2] = bv[1]; bi2[2] = bi2[1];
            if (better(sc, idx, bv[0], bi2[0])) { bv[1] = bv[0]; bi2[1] = bi2[0]; bv[0] = sc; bi2[0] = idx; }
            else { bv[1] = sc; bi2[1] = idx; }
          } else { bv[2] = sc; bi2[2] = idx; }
        }
      }
    }
#pragma unroll
    for (int o = 0; o < 3; ++o) {
      int idx = bi2[o];
      int p = idx / VV, tk = idx - p * VV;
      sp[o] = p; stk[o] = tk;
      parent[b * KB + o] = p;
      tok_new[b * KB + o] = tk;
      lpt_new[b * KB + o] = bv[o];
      fin_new[b * KB + o] = fink[p] | (tk == EOS_TOK);
    }
  }
  __syncthreads();
  if (tid < KB * TT) {
    int kk = tid / TT, tt = tid - kk * TT;
    trj_new[(b * KB + kk) * TT + tt] = (tt == t) ? stk[kk] : trj_old[(b * KB + sp[kk]) * TT + tt];
  }
}

__global__ void gather_kernel(const int* __restrict__ parent,
    const double* __restrict__ h1p, const double* __restrict__ c1p,
    const double* __restrict__ h2p, const double* __restrict__ c2p,
    double* __restrict__ h1s, double* __restrict__ c1s,
    double* __restrict__ h2s, double* __restrict__ c2s) {
  int idx = blockIdx.x * 256 + threadIdx.x;
  if (idx >= ROWS * (HH / 2)) return;
  int row = idx >> 9, jj = (idx & 511) << 1;
  int b = row / KB;
  int p = parent[row];
  size_t src = ((size_t)(b * KB + p) << 10) + jj;
  size_t dst = ((size_t)row << 10) + jj;
  *(double2*)&h1s[dst] = *(const double2*)&h1p[src];
  *(double2*)&c1s[dst] = *(const double2*)&c1p[src];
  *(double2*)&h2s[dst] = *(const double2*)&h2p[src];
  *(double2*)&c2s[dst] = *(const double2*)&c2p[src];
}

__global__ void out_kernel(const int* __restrict__ trj, const double* __restrict__ lpt,
                           float* __restrict__ out) {
  int idx = blockIdx.x * 256 + threadIdx.x;
  if (idx < BB * TT * KB) {
    int k = idx % KB;
    int rest = idx / KB;
    int t = rest % TT;
    int b = rest / TT;
    out[idx] = (float)trj[((size_t)(b * KB + k)) * TT + t];
  }
  if (idx < ROWS) out[BB * TT * KB + idx] = (float)lpt[idx];
}

// ---------------- host ----------------
extern "C" void kernel_launch(void* const* d_in, const int* in_sizes, int n_in,
                              void* d_out, int out_size, void* d_ws, size_t ws_size,
                              hipStream_t stream) {
  const float* features = (const float*)d_in[0];
  const float* E = (const float*)d_in[1];
  const float* Wi1 = (const float*)d_in[2];
  const float* Wh1 = (const float*)d_in[3];
  const float* b1 = (const float*)d_in[4];
  const float* Wi2 = (const float*)d_in[5];
  const float* Wh2 = (const float*)d_in[6];
  const float* b2 = (const float*)d_in[7];
  const float* Wva = (const float*)d_in[8];
  const float* bva = (const float*)d_in[9];
  const float* Wha = (const float*)d_in[10];
  const float* bha = (const float*)d_in[11];
  const float* wa = (const float*)d_in[12];
  const float* Wout = (const float*)d_in[13];
  const float* bout = (const float*)d_in[14];
  float* out = (float*)d_out;

  // ck = Ktot/S exact multiples of GKC=32; segment bases 32-aligned.
  const int SF = 4, SV = 8, S1 = 8, SH = 32, S2 = 8, SL = 4;

  double* base = (double*)d_ws;
  size_t off = 0;
  auto A = [&](size_t n) { double* p = base + off; off += n; return p; };
  double* featP = A((size_t)BB * RR * PH_);
  double* vme = A((size_t)BB * VD);
  double* gv1 = A((size_t)BB * 4 * HH);
  double* emb96 = A((size_t)ROWS * ED);
  double* vhat = A((size_t)ROWS * VD);
  double* h1s = A((size_t)ROWS * HH);
  double* c1s = A((size_t)ROWS * HH);
  double* h2s = A((size_t)ROWS * HH);
  double* c2s = A((size_t)ROWS * HH);
  double* h1p = A((size_t)ROWS * HH);
  double* c1p = A((size_t)ROWS * HH);
  double* h2p = A((size_t)ROWS * HH);
  double* c2p = A((size_t)ROWS * HH);
  double* b1d = A(4 * HH);
  double* b2d = A(4 * HH);
  double* bvad = A(PH_);
  double* bhad = A(PH_);
  double* wad = A(PH_);
  double* boutd = A(VV);
  double* cmS = A((size_t)ROWS * 8);
  double* csS = A((size_t)ROWS * 8);
  double* cvS = A((size_t)ROWS * 8 * 3);
  size_t arena_sz = (size_t)S1 * ROWS * 4 * HH;
  { size_t t2 = (size_t)S2 * ROWS * 4 * HH; if (t2 > arena_sz) arena_sz = t2; }
  { size_t tl = (size_t)SL * ROWS * VV;     if (tl > arena_sz) arena_sz = tl; }
  { size_t tv = (size_t)SV * BB * 4 * HH;   if (tv > arena_sz) arena_sz = tv; }
  { size_t tp = (size_t)BB * RR * VD + (size_t)SF * BB * RR * PH_;
    if (tp > arena_sz) arena_sz = tp; }
  double* arena = A(arena_sz);
  double* featF = arena;
  double* pF2 = arena + (size_t)BB * RR * VD;
  double* pV = arena;
  double* pG = arena;
  double* pL = arena;
  double* pH = A((size_t)SH * ROWS * PH_);
  double* lptA = A(ROWS);
  double* lptB = A(ROWS);
  int* ip = (int*)(base + off);
  int* tokA = ip; ip += ROWS;
  int* tokB = ip; ip += ROWS;
  int* finA = ip; ip += ROWS;
  int* finB = ip; ip += ROWS;
  int* par = ip; ip += ROWS;
  int* ciS = ip; ip += ROWS * 8 * 3;
  int* trjA = ip; ip += ROWS * TT;
  int* trjB = ip; ip += ROWS * TT;
  int* rowmap = ip; ip += 256;
  int* colmap = ip; ip += 256;

  mfma_probe<<<1, 64, 0, stream>>>(rowmap, colmap);
  init_kernel<<<(ROWS * HH + 255) / 256, 256, 0, stream>>>(h1s, c1s, h2s, c2s, tokA, lptA, finA, trjA);
  conv_kernel<<<(VV + 255) / 256, 256, 0, stream>>>(b1, b2, bva, bha, wa, bout,
                                                    b1d, b2d, bvad, bhad, wad, boutd);
  vmean_kernel<<<(BB * VD + 255) / 256, 256, 0, stream>>>(features, vme);
  convf_kernel<<<(BB * RR * VD + 255) / 256, 256, 0, stream>>>(features, featF, BB * RR * VD);
  {  // featP = features @ Wva.T + bva  [1152,256]
    GemmA a{};
    a.seg[0] = Seg{featF, Wva, VD, VD, 0, 0};
    a.nseg = 1; a.Mtot = BB * RR; a.N = PH_; a.Ktot = VD;
    dim3 g((PH_ + GBN - 1) / GBN, SF, (BB * RR + 95) / 96);
    gemm_f64<<<g, 256, 0, stream>>>(a, pF2, rowmap, colmap);
    reduce_bias_kernel<<<(BB * RR * PH_ + 255) / 256, 256, 0, stream>>>(featP, pF2, bvad, BB * RR, PH_, SF);
  }
  {  // gv1 = vme @ Wi1[:,1024:3072].T + b1  [32,4096]
    GemmA a{};
    a.seg[0] = Seg{vme, Wi1, VD, 3584, 1024, 0};
    a.nseg = 1; a.Mtot = BB; a.N = 4 * HH; a.Ktot = VD;
    dim3 g((4 * HH + GBN - 1) / GBN, SV, 1);
    gemm_f64<<<g, 256, 0, stream>>>(a, pV, rowmap, colmap);
    reduce_bias_kernel<<<(BB * 4 * HH + 255) / 256, 256, 0, stream>>>(gv1, pV, b1d, BB, 4 * HH, SV);
  }

  int *tokC = tokA, *tokN = tokB, *finC = finA, *finN = finB, *trjC = trjA, *trjN = trjB;
  double *lptC = lptA, *lptN = lptB;
  for (int t = 0; t < TT; ++t) {
    embed_kernel<<<(ROWS * ED + 255) / 256, 256, 0, stream>>>(tokC, E, emb96);
    {  // gates1: [h2s, emb, h1s] @ [Wi1 | Wh1]   Ktot=2560, ck=320
      GemmA a{};
      a.seg[0] = Seg{h2s, Wi1, HH, 3584, 0, 0};
      a.seg[1] = Seg{emb96, Wi1, ED, 3584, 3072, 1024};
      a.seg[2] = Seg{h1s, Wh1, HH, HH, 0, 1536};
      a.nseg = 3; a.Mtot = ROWS; a.N = 4 * HH; a.Ktot = 2560;
      dim3 g((4 * HH + GBN - 1) / GBN, S1, 1);
      gemm_f64<<<g, 256, 0, stream>>>(a, pG, rowmap, colmap);
    }
    lstm_kernel<<<(ROWS * (HH / 2) + 255) / 256, 256, 0, stream>>>(pG, S1, nullptr, gv1, c1s, h1p, c1p);
    {  // hp = h1p @ Wha.T   ck=32
      GemmA a{};
      a.seg[0] = Seg{h1p, Wha, HH, HH, 0, 0};
      a.nseg = 1; a.Mtot = ROWS; a.N = PH_; a.Ktot = HH;
      dim3 g((PH_ + GBN - 1) / GBN, SH, 1);
      gemm_f64<<<g, 256, 0, stream>>>(a, pH, rowmap, colmap);
    }
    attn_kernel<<<ROWS, 256, 0, stream>>>(pH, SH, bhad, featP, features, wad, vhat);
    {  // gates2: [h1p, vhat, h2s] @ [Wi2 | Wh2]   Ktot=4096, ck=512
      GemmA a{};
      a.seg[0] = Seg{h1p, Wi2, HH, 3072, 0, 0};
      a.seg[1] = Seg{vhat, Wi2, VD, 3072, 1024, 1024};
      a.seg[2] = Seg{h2s, Wh2, HH, HH, 0, 3072};
      a.nseg = 3; a.Mtot = ROWS; a.N = 4 * HH; a.Ktot = 4096;
      dim3 g((4 * HH + GBN - 1) / GBN, S2, 1);
      gemm_f64<<<g, 256, 0, stream>>>(a, pG, rowmap, colmap);
    }
    lstm_kernel<<<(ROWS * (HH / 2) + 255) / 256, 256, 0, stream>>>(pG, S2, b2d, nullptr, c2s, h2p, c2p);
    {  // logits partials = h2p @ Wout.T
      GemmA a{};
      a.seg[0] = Seg{h2p, Wout, HH, HH, 0, 0};
      a.nseg = 1; a.Mtot = ROWS; a.N = VV; a.Ktot = HH;
      dim3 g((VV + GBN - 1) / GBN, SL, 1);
      gemm_f64<<<g, 256, 0, stream>>>(a, pL, rowmap, colmap);
    }
    lchunk_kernel<<<dim3(ROWS, 8), 256, 0, stream>>>(pL, SL, boutd, tokC, t, cmS, csS, cvS, ciS);
    topk2_kernel<<<BB, 64, 0, stream>>>(cmS, csS, cvS, ciS, lptC, finC, trjC, t,
                                        tokN, lptN, finN, trjN, par);
    gather_kernel<<<(ROWS * (HH / 2) + 255) / 256, 256, 0, stream>>>(par, h1p, c1p, h2p, c2p,
                                                                     h1s, c1s, h2s, c2s);
    { int* tmp; double* tf;
      tmp = tokC; tokC = tokN; tokN = tmp;
      tmp = finC; finC = finN; finN = tmp;
      tmp = trjC; trjC = trjN; trjN = tmp;
      tf = lptC; lptC = lptN; lptN = tf; }
  }
  out_kernel<<<(BB * TT * KB + 255) / 256, 256, 0, stream>>>(trjC, lptC, out);
}

// Round 21
// 5237.574 us; speedup vs baseline: 1.0200x; 1.0200x over previous
//
#include <hip/hip_runtime.h>
#include <math.h>

// DecoderTopDown beam-search decoder, FINAL (= round 19, proven 5.26ms best):
// f64 pipeline (fp32 barred: chain-order flips a near-tie token, R2-R8);
// MFMA-f64 16x16x4 GEMM with on-device-probed C/D layout (R17), conflict-free
// LDS swizzle (R19); fused logits->chunk-stats->topk tail (R12).
// R20's double-buffer regressed and is reverted.
#define BB 32
#define KB 3
#define TT 20
#define VV 10000
#define RR 36
#define ED 512
#define VD 2048
#define HH 1024
#define PH_ 256
#define ROWS 96
#define EOS_TOK 2

typedef double f64x4 __attribute__((ext_vector_type(4)));

struct Seg { const double* X; const float* W; int ldx; int ldw; int woff; int kbeg; };
struct GemmA { Seg seg[3]; int nseg; int Mtot; int N; int Ktot; };

#define GBN 64
#define GKC 32
#define PX 34   // X row pad (doubles)
#define PW 36   // W row pad (floats)

// Probe the C/D fragment layout of v_mfma_f64_16x16x4 (proven R17).
__global__ void mfma_probe(int* __restrict__ rowmap, int* __restrict__ colmap) {
  int lane = threadIdx.x & 63;
  f64x4 z = {0.0, 0.0, 0.0, 0.0};
  double a1 = (double)(lane & 15), b1 = 1.0;
  f64x4 d1 = __builtin_amdgcn_mfma_f64_16x16x4f64(a1, b1, z, 0, 0, 0);
  double a2 = 1.0, b2 = (double)(lane & 15);
  f64x4 d2 = __builtin_amdgcn_mfma_f64_16x16x4f64(a2, b2, z, 0, 0, 0);
#pragma unroll
  for (int r = 0; r < 4; ++r) {
    rowmap[lane * 4 + r] = (int)(d1[r] * 0.25 + 0.5);
    colmap[lane * 4 + r] = (int)(d2[r] * 0.25 + 0.5);
  }
}

__global__ __launch_bounds__(256) void gemm_f64(GemmA a, double* __restrict__ part,
    const int* __restrict__ rowmap, const int* __restrict__ colmap) {
  __shared__ double Xs[96][PX];
  __shared__ float  Ws[GBN][PW];
  const int tid = threadIdx.x;
  const int n0 = blockIdx.x * GBN;
  const int s = blockIdx.y;
  const int m0 = blockIdx.z * 96;
  const int S = gridDim.y;
  const int ck = a.Ktot / S;        // host: divisible, multiple of GKC
  const int ks = s * ck;
  const int nch = ck / GKC;
  const int wave = tid >> 6, lane = tid & 63;
  const int lrow = lane & 15, lk = lane >> 4;
  const int xo = (lrow >> 3) & 1;          // X read swizzle offset
  const int wo = ((lrow >> 3) & 1) << 1;   // W read swizzle offset

  f64x4 acc[6];
#pragma unroll
  for (int r = 0; r < 6; ++r) acc[r] = (f64x4){0.0, 0.0, 0.0, 0.0};

  double2 xst[6];
  float4 wst[2];

  auto issue = [&](int k0) {
    int si = 0;
    for (int i = 1; i < a.nseg; ++i) if (k0 >= a.seg[i].kbeg) si = i;
    Seg sg = a.seg[si];
    int kl = k0 - sg.kbeg;
#pragma unroll
    for (int j = 0; j < 6; ++j) {      // X: 96 rows x 16 double2 cols
      int i = tid + 256 * j;
      int m = i >> 4, q = (i & 15) << 1;
      int mg = m0 + m;
      double2 v; v.x = 0.0; v.y = 0.0;
      if (mg < a.Mtot) v = *(const double2*)&sg.X[(size_t)mg * sg.ldx + kl + q];
      xst[j] = v;
    }
#pragma unroll
    for (int j = 0; j < 2; ++j) {      // W: 64 rows x 8 float4 cols
      int i = tid + 256 * j;
      int n = i >> 3, q = (i & 7) << 2;
      int ng = n0 + n;
      float4 v = {0.f, 0.f, 0.f, 0.f};
      if (ng < a.N) v = *(const float4*)&sg.W[(size_t)ng * sg.ldw + sg.woff + kl + q];
      wst[j] = v;
    }
  };

  issue(ks);
  for (int ch = 0; ch < nch; ++ch) {
    __syncthreads();
#pragma unroll
    for (int j = 0; j < 6; ++j) {
      int i = tid + 256 * j;
      int m = i >> 4, q = (i & 15) << 1;
      int o = (m >> 3) & 1;
      Xs[m][q + o] = xst[j].x;
      Xs[m][q + 1 + o] = xst[j].y;
    }
#pragma unroll
    for (int j = 0; j < 2; ++j) {
      int i = tid + 256 * j;
      int n = i >> 3, q = (i & 7) << 2;
      int o = ((n >> 3) & 1) << 1;
      Ws[n][q + o] = wst[j].x;
      Ws[n][q + 1 + o] = wst[j].y;
      Ws[n][q + 2 + o] = wst[j].z;
      Ws[n][q + 3 + o] = wst[j].w;
    }
    __syncthreads();
    if (ch + 1 < nch) issue(ks + (ch + 1) * GKC);
#pragma unroll
    for (int kq = 0; kq < GKC; kq += 4) {
      double b = (double)Ws[16 * wave + lrow][kq + lk + wo];
#pragma unroll
      for (int r = 0; r < 6; ++r) {
        double av = Xs[16 * r + lrow][kq + lk + xo];
        acc[r] = __builtin_amdgcn_mfma_f64_16x16x4f64(av, b, acc[r], 0, 0, 0);
      }
    }
  }
  int rmap[4], cmap[4];
#pragma unroll
  for (int i = 0; i < 4; ++i) { rmap[i] = rowmap[lane * 4 + i]; cmap[i] = colmap[lane * 4 + i]; }
#pragma unroll
  for (int r = 0; r < 6; ++r) {
#pragma unroll
    for (int i = 0; i < 4; ++i) {
      int mg = m0 + 16 * r + rmap[i];
      int col = n0 + 16 * wave + cmap[i];
      if (mg < a.Mtot && col < a.N)
        part[((size_t)s * a.Mtot + mg) * a.N + col] = acc[r][i];
    }
  }
}

__global__ void convf_kernel(const float* __restrict__ s, double* __restrict__ d, int n) {
  int i = blockIdx.x * 256 + threadIdx.x;
  if (i < n) d[i] = (double)s[i];
}

__global__ void conv_kernel(const float* b1, const float* b2, const float* bva,
                            const float* bha, const float* wa, const float* bout,
                            double* b1d, double* b2d, double* bvad,
                            double* bhad, double* wad, double* boutd) {
  int i = blockIdx.x * 256 + threadIdx.x;
  if (i < 4 * HH) { b1d[i] = (double)b1[i]; b2d[i] = (double)b2[i]; }
  if (i < PH_) { bvad[i] = (double)bva[i]; bhad[i] = (double)bha[i]; wad[i] = (double)wa[i]; }
  if (i < VV) boutd[i] = (double)bout[i];
}

__global__ void init_kernel(double* h1s, double* c1s, double* h2s, double* c2s,
                            int* tok, double* lpt, int* fin, int* trj) {
  int idx = blockIdx.x * 256 + threadIdx.x;
  if (idx < ROWS * HH) { h1s[idx] = 0.0; c1s[idx] = 0.0; h2s[idx] = 0.0; c2s[idx] = 0.0; }
  if (idx < ROWS) { tok[idx] = 1; lpt[idx] = 0.0; fin[idx] = 0; }
  if (idx < ROWS * TT) trj[idx] = 0;
}

__global__ void vmean_kernel(const float* __restrict__ features, double* __restrict__ vme) {
  int idx = blockIdx.x * 256 + threadIdx.x;
  if (idx >= BB * VD) return;
  int b = idx / VD, d = idx - b * VD;
  double sum = 0.0;
  for (int r = 0; r < RR; ++r) sum += (double)features[((size_t)b * RR + r) * VD + d];
  vme[idx] = sum / (double)RR;
}

__global__ void reduce_bias_kernel(double* __restrict__ out, const double* __restrict__ parts,
                                   const double* __restrict__ bias, int rows, int cols, int S) {
  int idx = blockIdx.x * 256 + threadIdx.x;
  if (idx >= rows * cols) return;
  int c = idx % cols;
  double acc = bias[c];
  for (int s = 0; s < S; ++s) acc += parts[(size_t)s * rows * cols + idx];
  out[idx] = acc;
}

__global__ void embed_kernel(const int* __restrict__ tok, const float* __restrict__ E,
                             double* __restrict__ emb) {
  int idx = blockIdx.x * 256 + threadIdx.x;
  if (idx >= ROWS * ED) return;
  int row = idx >> 9, e2 = idx & (ED - 1);
  emb[idx] = (double)E[(size_t)tok[row] * ED + e2];
}

__global__ void lstm_kernel(const double* __restrict__ gP, int S,
                            const double* __restrict__ bias_col, const double* __restrict__ bias_row,
                            const double* __restrict__ c_in, double* __restrict__ h_out,
                            double* __restrict__ c_out) {
  int idx = blockIdx.x * 256 + threadIdx.x;
  if (idx >= ROWS * (HH / 2)) return;
  int row = idx >> 9, jj = (idx & 511) << 1;
  int b = row / KB;
  double2 g[4];
#pragma unroll
  for (int gi = 0; gi < 4; ++gi) {
    double2 acc;
    if (bias_col) acc = *(const double2*)&bias_col[gi * HH + jj];
    else          acc = *(const double2*)&bias_row[(size_t)b * 4 * HH + gi * HH + jj];
    for (int s = 0; s < S; ++s) {
      double2 p = *(const double2*)&gP[((size_t)s * ROWS + row) * (4 * HH) + gi * HH + jj];
      acc.x += p.x; acc.y += p.y;
    }
    g[gi] = acc;
  }
  double2 cp = *(const double2*)&c_in[((size_t)row << 10) + jj];
  double2 hv, cv;
  {
    double ig = 1.0 / (1.0 + exp(-g[0].x)), fg = 1.0 / (1.0 + exp(-g[1].x));
    double gg = tanh(g[2].x), og = 1.0 / (1.0 + exp(-g[3].x));
    cv.x = fg * cp.x + ig * gg; hv.x = og * tanh(cv.x);
  }
  {
    double ig = 1.0 / (1.0 + exp(-g[0].y)), fg = 1.0 / (1.0 + exp(-g[1].y));
    double gg = tanh(g[2].y), og = 1.0 / (1.0 + exp(-g[3].y));
    cv.y = fg * cp.y + ig * gg; hv.y = og * tanh(cv.y);
  }
  *(double2*)&h_out[((size_t)row << 10) + jj] = hv;
  *(double2*)&c_out[((size_t)row << 10) + jj] = cv;
}

__global__ __launch_bounds__(256) void attn_kernel(const double* __restrict__ hpP, int S,
    const double* __restrict__ bha, const double* __restrict__ featP,
    const float* __restrict__ features, const double* __restrict__ wa,
    double* __restrict__ vhat) {
  int row = blockIdx.x;
  int b = row / KB;
  int tid = threadIdx.x;
  __shared__ double hp[PH_];
  __shared__ double e[RR];
  {
    double v = bha[tid];
    for (int s = 0; s < S; ++s) v += hpP[((size_t)s * ROWS + row) * PH_ + tid];
    hp[tid] = v;
  }
  __syncthreads();
  int wv = tid >> 6, ln = tid & 63;
  for (int r = wv * 9; r < wv * 9 + 9; ++r) {
    double p = 0.0;
#pragma unroll
    for (int i = 0; i < 4; ++i) {
      int ph = ln * 4 + i;
      p += tanh(featP[((size_t)b * RR + r) * PH_ + ph] + hp[ph]) * wa[ph];
    }
#pragma unroll
    for (int o = 32; o; o >>= 1) p += __shfl_down(p, o);
    if (ln == 0) e[r] = p;
  }
  __syncthreads();
  if (tid == 0) {
    double m = e[0];
    for (int r = 1; r < RR; ++r) m = fmax(m, e[r]);
    double se = 0.0;
    for (int r = 0; r < RR; ++r) se += exp(e[r] - m);
    for (int r = 0; r < RR; ++r) e[r] = exp(e[r] - m) / se;
  }
  __syncthreads();
  for (int d = tid; d < VD; d += 256) {
    double acc2 = 0.0;
    for (int r = 0; r < RR; ++r) acc2 += e[r] * (double)features[((size_t)b * RR + r) * VD + d];
    vhat[(size_t)row * VD + d] = acc2;
  }
}

__device__ inline double wred_maxd(double v) {
#pragma unroll
  for (int o = 32; o; o >>= 1) v = fmax(v, __shfl_down(v, o));
  return v;
}
__device__ inline double wred_sumd(double v) {
#pragma unroll
  for (int o = 32; o; o >>= 1) v += __shfl_down(v, o);
  return v;
}

__device__ inline bool better(double va, int ia, double vb, int ib) {
  if (va != vb) return va > vb;
  return (unsigned)ia < (unsigned)ib;
}

__global__ __launch_bounds__(256) void lchunk_kernel(const double* __restrict__ lP, int S,
    const double* __restrict__ bout, const int* __restrict__ tok_old, int t,
    double* __restrict__ cm, double* __restrict__ cs,
    double* __restrict__ cv, int* __restrict__ ci) {
  const int CHV = VV / 8;   // 1250
  int row = blockIdx.x, chk = blockIdx.y, tid = threadIdx.x;
  int v0 = chk * CHV;
  int tokp = tok_old[row];
  double r[5];
  double lmax = -1.0e300;
#pragma unroll
  for (int j = 0; j < 5; ++j) {
    int vv = tid + (j << 8);
    double acc = -1.0e300;
    if (vv < CHV) {
      int v = v0 + vv;
      acc = bout[v];
      for (int s = 0; s < S; ++s) acc += lP[((size_t)s * ROWS + row) * VV + v];
      lmax = fmax(lmax, acc);
    }
    r[j] = acc;
  }
  __shared__ double red[4];
  double m = wred_maxd(lmax);
  if ((tid & 63) == 0) red[tid >> 6] = m;
  __syncthreads();
  m = fmax(fmax(red[0], red[1]), fmax(red[2], red[3]));
  double se = 0.0;
#pragma unroll
  for (int j = 0; j < 5; ++j) {
    int vv = tid + (j << 8);
    if (vv < CHV) se += exp(r[j] - m);
  }
  se = wred_sumd(se);
  __syncthreads();
  if ((tid & 63) == 0) red[tid >> 6] = se;
  __syncthreads();
  se = red[0] + red[1] + red[2] + red[3];
  double lv[3] = {-INFINITY, -INFINITY, -INFINITY};
  int li[3] = {-1, -1, -1};
#pragma unroll
  for (int j = 0; j < 5; ++j) {
    int vv = tid + (j << 8);
    if (vv >= CHV) continue;
    int v = v0 + vv;
    double sc = r[j];
    if (t > 0 && v == tokp) sc -= 1e4;
    if (better(sc, v, lv[2], li[2])) {
      if (better(sc, v, lv[1], li[1])) {
        lv[2] = lv[1]; li[2] = li[1];
        if (better(sc, v, lv[0], li[0])) { lv[1] = lv[0]; li[1] = li[0]; lv[0] = sc; li[0] = v; }
        else { lv[1] = sc; li[1] = v; }
      } else { lv[2] = sc; li[2] = v; }
    }
  }
  __shared__ double sv[256 * 3];
  __shared__ int si[256 * 3];
  sv[tid * 3 + 0] = lv[0]; sv[tid * 3 + 1] = lv[1]; sv[tid * 3 + 2] = lv[2];
  si[tid * 3 + 0] = li[0]; si[tid * 3 + 1] = li[1]; si[tid * 3 + 2] = li[2];
  for (int off2 = 128; off2 >= 1; off2 >>= 1) {
    __syncthreads();
    if (tid < off2) {
      double av[3], bv2[3]; int ai3[3], bi3[3];
#pragma unroll
      for (int j = 0; j < 3; ++j) {
        av[j] = sv[tid * 3 + j]; ai3[j] = si[tid * 3 + j];
        bv2[j] = sv[(tid + off2) * 3 + j]; bi3[j] = si[(tid + off2) * 3 + j];
      }
      double mv[3]; int mi[3];
      int ai = 0, bi = 0;
#pragma unroll
      for (int o = 0; o < 3; ++o) {
        if (better(av[ai], ai3[ai], bv2[bi], bi3[bi])) { mv[o] = av[ai]; mi[o] = ai3[ai]; ++ai; }
        else { mv[o] = bv2[bi]; mi[o] = bi3[bi]; ++bi; }
      }
#pragma unroll
      for (int j = 0; j < 3; ++j) { sv[tid * 3 + j] = mv[j]; si[tid * 3 + j] = mi[j]; }
    }
  }
  __syncthreads();
  if (tid == 0) {
    int o = row * 8 + chk;
    cm[o] = m; cs[o] = se;
    cv[o * 3 + 0] = sv[0]; cv[o * 3 + 1] = sv[1]; cv[o * 3 + 2] = sv[2];
    ci[o * 3 + 0] = si[0]; ci[o * 3 + 1] = si[1]; ci[o * 3 + 2] = si[2];
  }
}

__global__ __launch_bounds__(64) void topk2_kernel(
    const double* __restrict__ cm, const double* __restrict__ cs,
    const double* __restrict__ cv, const int* __restrict__ ci,
    const double* __restrict__ lpt_old, const int* __restrict__ fin_old,
    const int* __restrict__ trj_old, int t,
    int* __restrict__ tok_new, double* __restrict__ lpt_new, int* __restrict__ fin_new,
    int* __restrict__ trj_new, int* __restrict__ parent) {
  int b = blockIdx.x, tid = threadIdx.x;
  __shared__ double candv[72];
  __shared__ int candi[72];
  __shared__ int cnt[3];
  __shared__ int fink[3];
  __shared__ int sp[3], stk[3];
  if (tid < KB) {
    int row = b * KB + tid;
    double lpt = lpt_old[row];
    int fin = fin_old[row];
    fink[tid] = fin;
    int base = tid * 24;
    if (t == 0 && tid > 0) {
      cnt[tid] = 0;
    } else if (fin) {
      candv[base] = lpt;
      candi[base] = tid * VV + EOS_TOK;
      cnt[tid] = 1;
    } else {
      double M = -1.0e300;
      for (int c = 0; c < 8; ++c) M = fmax(M, cm[row * 8 + c]);
      double SE = 0.0;
      for (int c = 0; c < 8; ++c) SE += cs[row * 8 + c] * exp(cm[row * 8 + c] - M);
      double l = log(SE);
      int n = 0;
      for (int c = 0; c < 8; ++c) {
#pragma unroll
        for (int s3 = 0; s3 < 3; ++s3) {
          double val = cv[(row * 8 + c) * 3 + s3];
          int idx = ci[(row * 8 + c) * 3 + s3];
          candv[base + n] = lpt + ((val - M) - l);
          candi[base + n] = tid * VV + idx;
          ++n;
        }
      }
      cnt[tid] = n;
    }
  }
  __syncthreads();
  if (tid == 0) {
    double bv[3] = {-INFINITY, -INFINITY, -INFINITY};
    int bi2[3] = {-1, -1, -1};
    for (int k = 0; k < KB; ++k) {
      for (int j = 0; j < cnt[k]; ++j) {
        double sc = candv[k * 24 + j];
        int idx = candi[k * 24 + j];
        if (better(sc, idx, bv[2], bi2[2])) {
          if (better(sc, idx, bv[1], bi2[1])) {
            bv[2] = bv[1]; bi2[2] = bi2[1];
            if (better(sc, idx, bv[0], bi2[0])) { bv[1] = bv[0]; bi2[1] = bi2[0]; bv[0] = sc; bi2[0] = idx; }
            else { bv[1] = sc; bi2[1] = idx; }
          } else { bv[2] = sc; bi2[2] = idx; }
        }
      }
    }
#pragma unroll
    for (int o = 0; o < 3; ++o) {
      int idx = bi2[o];
      int p = idx / VV, tk = idx - p * VV;
      sp[o] = p; stk[o] = tk;
      parent[b * KB + o] = p;
      tok_new[b * KB + o] = tk;
      lpt_new[b * KB + o] = bv[o];
      fin_new[b * KB + o] = fink[p] | (tk == EOS_TOK);
    }
  }
  __syncthreads();
  if (tid < KB * TT) {
    int kk = tid / TT, tt = tid - kk * TT;
    trj_new[(b * KB + kk) * TT + tt] = (tt == t) ? stk[kk] : trj_old[(b * KB + sp[kk]) * TT + tt];
  }
}

__global__ void gather_kernel(const int* __restrict__ parent,
    const double* __restrict__ h1p, const double* __restrict__ c1p,
    const double* __restrict__ h2p, const double* __restrict__ c2p,
    double* __restrict__ h1s, double* __restrict__ c1s,
    double* __restrict__ h2s, double* __restrict__ c2s) {
  int idx = blockIdx.x * 256 + threadIdx.x;
  if (idx >= ROWS * (HH / 2)) return;
  int row = idx >> 9, jj = (idx & 511) << 1;
  int b = row / KB;
  int p = parent[row];
  size_t src = ((size_t)(b * KB + p) << 10) + jj;
  size_t dst = ((size_t)row << 10) + jj;
  *(double2*)&h1s[dst] = *(const double2*)&h1p[src];
  *(double2*)&c1s[dst] = *(const double2*)&c1p[src];
  *(double2*)&h2s[dst] = *(const double2*)&h2p[src];
  *(double2*)&c2s[dst] = *(const double2*)&c2p[src];
}

__global__ void out_kernel(const int* __restrict__ trj, const double* __restrict__ lpt,
                           float* __restrict__ out) {
  int idx = blockIdx.x * 256 + threadIdx.x;
  if (idx < BB * TT * KB) {
    int k = idx % KB;
    int rest = idx / KB;
    int t = rest % TT;
    int b = rest / TT;
    out[idx] = (float)trj[((size_t)(b * KB + k)) * TT + t];
  }
  if (idx < ROWS) out[BB * TT * KB + idx] = (float)lpt[idx];
}

// ---------------- host ----------------
extern "C" void kernel_launch(void* const* d_in, const int* in_sizes, int n_in,
                              void* d_out, int out_size, void* d_ws, size_t ws_size,
                              hipStream_t stream) {
  const float* features = (const float*)d_in[0];
  const float* E = (const float*)d_in[1];
  const float* Wi1 = (const float*)d_in[2];
  const float* Wh1 = (const float*)d_in[3];
  const float* b1 = (const float*)d_in[4];
  const float* Wi2 = (const float*)d_in[5];
  const float* Wh2 = (const float*)d_in[6];
  const float* b2 = (const float*)d_in[7];
  const float* Wva = (const float*)d_in[8];
  const float* bva = (const float*)d_in[9];
  const float* Wha = (const float*)d_in[10];
  const float* bha = (const float*)d_in[11];
  const float* wa = (const float*)d_in[12];
  const float* Wout = (const float*)d_in[13];
  const float* bout = (const float*)d_in[14];
  float* out = (float*)d_out;

  // ck = Ktot/S exact multiples of GKC=32; segment bases 32-aligned.
  const int SF = 4, SV = 8, S1 = 8, SH = 32, S2 = 8, SL = 4;

  double* base = (double*)d_ws;
  size_t off = 0;
  auto A = [&](size_t n) { double* p = base + off; off += n; return p; };
  double* featP = A((size_t)BB * RR * PH_);
  double* vme = A((size_t)BB * VD);
  double* gv1 = A((size_t)BB * 4 * HH);
  double* emb96 = A((size_t)ROWS * ED);
  double* vhat = A((size_t)ROWS * VD);
  double* h1s = A((size_t)ROWS * HH);
  double* c1s = A((size_t)ROWS * HH);
  double* h2s = A((size_t)ROWS * HH);
  double* c2s = A((size_t)ROWS * HH);
  double* h1p = A((size_t)ROWS * HH);
  double* c1p = A((size_t)ROWS * HH);
  double* h2p = A((size_t)ROWS * HH);
  double* c2p = A((size_t)ROWS * HH);
  double* b1d = A(4 * HH);
  double* b2d = A(4 * HH);
  double* bvad = A(PH_);
  double* bhad = A(PH_);
  double* wad = A(PH_);
  double* boutd = A(VV);
  double* cmS = A((size_t)ROWS * 8);
  double* csS = A((size_t)ROWS * 8);
  double* cvS = A((size_t)ROWS * 8 * 3);
  size_t arena_sz = (size_t)S1 * ROWS * 4 * HH;
  { size_t t2 = (size_t)S2 * ROWS * 4 * HH; if (t2 > arena_sz) arena_sz = t2; }
  { size_t tl = (size_t)SL * ROWS * VV;     if (tl > arena_sz) arena_sz = tl; }
  { size_t tv = (size_t)SV * BB * 4 * HH;   if (tv > arena_sz) arena_sz = tv; }
  { size_t tp = (size_t)BB * RR * VD + (size_t)SF * BB * RR * PH_;
    if (tp > arena_sz) arena_sz = tp; }
  double* arena = A(arena_sz);
  double* featF = arena;
  double* pF2 = arena + (size_t)BB * RR * VD;
  double* pV = arena;
  double* pG = arena;
  double* pL = arena;
  double* pH = A((size_t)SH * ROWS * PH_);
  double* lptA = A(ROWS);
  double* lptB = A(ROWS);
  int* ip = (int*)(base + off);
  int* tokA = ip; ip += ROWS;
  int* tokB = ip; ip += ROWS;
  int* finA = ip; ip += ROWS;
  int* finB = ip; ip += ROWS;
  int* par = ip; ip += ROWS;
  int* ciS = ip; ip += ROWS * 8 * 3;
  int* trjA = ip; ip += ROWS * TT;
  int* trjB = ip; ip += ROWS * TT;
  int* rowmap = ip; ip += 256;
  int* colmap = ip; ip += 256;

  mfma_probe<<<1, 64, 0, stream>>>(rowmap, colmap);
  init_kernel<<<(ROWS * HH + 255) / 256, 256, 0, stream>>>(h1s, c1s, h2s, c2s, tokA, lptA, finA, trjA);
  conv_kernel<<<(VV + 255) / 256, 256, 0, stream>>>(b1, b2, bva, bha, wa, bout,
                                                    b1d, b2d, bvad, bhad, wad, boutd);
  vmean_kernel<<<(BB * VD + 255) / 256, 256, 0, stream>>>(features, vme);
  convf_kernel<<<(BB * RR * VD + 255) / 256, 256, 0, stream>>>(features, featF, BB * RR * VD);
  {  // featP = features @ Wva.T + bva  [1152,256]
    GemmA a{};
    a.seg[0] = Seg{featF, Wva, VD, VD, 0, 0};
    a.nseg = 1; a.Mtot = BB * RR; a.N = PH_; a.Ktot = VD;
    dim3 g((PH_ + GBN - 1) / GBN, SF, (BB * RR + 95) / 96);
    gemm_f64<<<g, 256, 0, stream>>>(a, pF2, rowmap, colmap);
    reduce_bias_kernel<<<(BB * RR * PH_ + 255) / 256, 256, 0, stream>>>(featP, pF2, bvad, BB * RR, PH_, SF);
  }
  {  // gv1 = vme @ Wi1[:,1024:3072].T + b1  [32,4096]
    GemmA a{};
    a.seg[0] = Seg{vme, Wi1, VD, 3584, 1024, 0};
    a.nseg = 1; a.Mtot = BB; a.N = 4 * HH; a.Ktot = VD;
    dim3 g((4 * HH + GBN - 1) / GBN, SV, 1);
    gemm_f64<<<g, 256, 0, stream>>>(a, pV, rowmap, colmap);
    reduce_bias_kernel<<<(BB * 4 * HH + 255) / 256, 256, 0, stream>>>(gv1, pV, b1d, BB, 4 * HH, SV);
  }

  int *tokC = tokA, *tokN = tokB, *finC = finA, *finN = finB, *trjC = trjA, *trjN = trjB;
  double *lptC = lptA, *lptN = lptB;
  for (int t = 0; t < TT; ++t) {
    embed_kernel<<<(ROWS * ED + 255) / 256, 256, 0, stream>>>(tokC, E, emb96);
    {  // gates1: [h2s, emb, h1s] @ [Wi1 | Wh1]   Ktot=2560, ck=320
      GemmA a{};
      a.seg[0] = Seg{h2s, Wi1, HH, 3584, 0, 0};
      a.seg[1] = Seg{emb96, Wi1, ED, 3584, 3072, 1024};
      a.seg[2] = Seg{h1s, Wh1, HH, HH, 0, 1536};
      a.nseg = 3; a.Mtot = ROWS; a.N = 4 * HH; a.Ktot = 2560;
      dim3 g((4 * HH + GBN - 1) / GBN, S1, 1);
      gemm_f64<<<g, 256, 0, stream>>>(a, pG, rowmap, colmap);
    }
    lstm_kernel<<<(ROWS * (HH / 2) + 255) / 256, 256, 0, stream>>>(pG, S1, nullptr, gv1, c1s, h1p, c1p);
    {  // hp = h1p @ Wha.T   ck=32
      GemmA a{};
      a.seg[0] = Seg{h1p, Wha, HH, HH, 0, 0};
      a.nseg = 1; a.Mtot = ROWS; a.N = PH_; a.Ktot = HH;
      dim3 g((PH_ + GBN - 1) / GBN, SH, 1);
      gemm_f64<<<g, 256, 0, stream>>>(a, pH, rowmap, colmap);
    }
    attn_kernel<<<ROWS, 256, 0, stream>>>(pH, SH, bhad, featP, features, wad, vhat);
    {  // gates2: [h1p, vhat, h2s] @ [Wi2 | Wh2]   Ktot=4096, ck=512
      GemmA a{};
      a.seg[0] = Seg{h1p, Wi2, HH, 3072, 0, 0};
      a.seg[1] = Seg{vhat, Wi2, VD, 3072, 1024, 1024};
      a.seg[2] = Seg{h2s, Wh2, HH, HH, 0, 3072};
      a.nseg = 3; a.Mtot = ROWS; a.N = 4 * HH; a.Ktot = 4096;
      dim3 g((4 * HH + GBN - 1) / GBN, S2, 1);
      gemm_f64<<<g, 256, 0, stream>>>(a, pG, rowmap, colmap);
    }
    lstm_kernel<<<(ROWS * (HH / 2) + 255) / 256, 256, 0, stream>>>(pG, S2, b2d, nullptr, c2s, h2p, c2p);
    {  // logits partials = h2p @ Wout.T
      GemmA a{};
      a.seg[0] = Seg{h2p, Wout, HH, HH, 0, 0};
      a.nseg = 1; a.Mtot = ROWS; a.N = VV; a.Ktot = HH;
      dim3 g((VV + GBN - 1) / GBN, SL, 1);
      gemm_f64<<<g, 256, 0, stream>>>(a, pL, rowmap, colmap);
    }
    lchunk_kernel<<<dim3(ROWS, 8), 256, 0, stream>>>(pL, SL, boutd, tokC, t, cmS, csS, cvS, ciS);
    topk2_kernel<<<BB, 64, 0, stream>>>(cmS, csS, cvS, ciS, lptC, finC, trjC, t,
                                        tokN, lptN, finN, trjN, par);
    gather_kernel<<<(ROWS * (HH / 2) + 255) / 256, 256, 0, stream>>>(par, h1p, c1p, h2p, c2p,
                                                                     h1s, c1s, h2s, c2s);
    { int* tmp; double* tf;
      tmp = tokC; tokC = tokN; tokN = tmp;
      tmp = finC; finC = finN; finN = tmp;
      tmp = trjC; trjC = trjN; trjN = tmp;
      tf = lptC; lptC = lptN; lptN = tf; }
  }
  out_kernel<<<(BB * TT * KB + 255) / 256, 256, 0, stream>>>(trjC, lptC, out);
}